// Round 7
// baseline (214.564 us; speedup 1.0000x reference)
//
#include <hip/hip_runtime.h>

// Problem constants
#define NB   4
#define NH   12
#define HD   64
#define CCH  768        // NH*HD
#define LQ   1024
#define SCALE 0.125f    // 1/sqrt(64)
#define STAB  4.0f      // constant softmax stabilizer (scores ~N(0,1), max~4)
#define WELE (CCH*CCH)  // 589824 elements per weight matrix

typedef unsigned short u16;
typedef __bf16 bf16x8 __attribute__((ext_vector_type(8)));
typedef unsigned short u16x8 __attribute__((ext_vector_type(8)));
typedef unsigned short u16x4 __attribute__((ext_vector_type(4)));
typedef float floatx4 __attribute__((ext_vector_type(4)));
typedef float floatx16 __attribute__((ext_vector_type(16)));

__device__ __forceinline__ float bf2f(u16 u) {
    union { unsigned int i; float f; } x; x.i = ((unsigned int)u) << 16; return x.f;
}
__device__ __forceinline__ u16 f2bf_u(float f) {
    union { float f; unsigned int i; } x; x.f = f;
    unsigned int i = x.i;
    return (u16)((i + 0x7FFFu + ((i >> 16) & 1u)) >> 16);   // RNE
}
// async global -> LDS, 16 B per lane; lds dst must be wave-uniform base
__device__ __forceinline__ void glds16(const u16* g, u16* l) {
    __builtin_amdgcn_global_load_lds(
        (const __attribute__((address_space(1))) unsigned int*)g,
        (__attribute__((address_space(3))) unsigned int*)l, 16, 0, 0);
}

// ---------------------------------------------------------------------------
// one-time weight conversion fp32 -> bf16 ([4][768*768]: wq,wk,wv,wo)
// ---------------------------------------------------------------------------
__global__ __launch_bounds__(256) void convert_w_kernel(
    const float* __restrict__ wq, const float* __restrict__ wk,
    const float* __restrict__ wv, const float* __restrict__ wo,
    u16* __restrict__ wb)
{
    const int p = blockIdx.y;
    const float* src = (p == 0) ? wq : (p == 1) ? wk : (p == 2) ? wv : wo;
    u16* dst = wb + (size_t)p * WELE;
    const int idx = (blockIdx.x * 256 + threadIdx.x) * 4;
    const float4 v = *reinterpret_cast<const float4*>(src + idx);
    u16x4 o;
    o[0] = f2bf_u(v.x); o[1] = f2bf_u(v.y); o[2] = f2bf_u(v.z); o[3] = f2bf_u(v.w);
    *reinterpret_cast<u16x4*>(dst + idx) = o;
}

// ---------------------------------------------------------------------------
// x [b][c][l] fp32  ->  xT [b][l][c] bf16   (64x64 LDS tile transpose)
// ---------------------------------------------------------------------------
__global__ __launch_bounds__(256) void transpose_x_kernel(
    const float* __restrict__ x, u16* __restrict__ xT)
{
    __shared__ u16 tile[64 * 68];
    const int l0 = blockIdx.x * 64, c0 = blockIdx.y * 64, b = blockIdx.z;
    const int t = threadIdx.x;
    const float* xb = x + (size_t)b * CCH * LQ;
    {
        const int l = t & 63, cg = t >> 6;
        for (int i = 0; i < 16; ++i) {
            const int c = cg * 16 + i;
            tile[c * 68 + l] = f2bf_u(xb[(size_t)(c0 + c) * LQ + l0 + l]);
        }
    }
    __syncthreads();
    {
        const int c = t & 63, lg = t >> 6;
        for (int i = 0; i < 16; ++i) {
            const int l = lg * 16 + i;
            xT[((size_t)b * LQ + l0 + l) * CCH + c0 + c] = tile[c * 68 + l];
        }
    }
}

// ---------------------------------------------------------------------------
// Tiled MFMA GEMM core: C = A (M x K) . B^T (N x K), both bf16 row-major-in-K.
// CTA 128x128, BK=64, global_load_lds staging with XOR-8 chunk swizzle.
// 4 waves (2x2), each 64x64 = 4x4 MFMA 16x16x32. 2-barrier K-loop (m97).
// ---------------------------------------------------------------------------
#define GEMM_CORE(Ag, Bg)                                                     \
    __shared__ __align__(16) u16 a_tile[128 * 64];                            \
    __shared__ __align__(16) u16 b_tile[128 * 64];                            \
    const int t = threadIdx.x;                                                \
    const int wave = t >> 6, lane = t & 63;                                   \
    const int quad = lane >> 4, l16 = lane & 15;                              \
    const int wm = (wave >> 1) * 64, wn = (wave & 1) * 64;                    \
    floatx4 acc[4][4];                                                        \
    _Pragma("unroll") for (int mi = 0; mi < 4; ++mi)                          \
        _Pragma("unroll") for (int ni = 0; ni < 4; ++ni)                      \
            _Pragma("unroll") for (int r = 0; r < 4; ++r) acc[mi][ni][r] = 0.f;\
    for (int k0 = 0; k0 < CCH; k0 += 64) {                                    \
        __syncthreads();                                                      \
        _Pragma("unroll") for (int i = 0; i < 4; ++i) {                       \
            const int sbase = wave * 256 + i * 64;                            \
            const int s = sbase + lane;                                       \
            const int m = s >> 3, pos = s & 7;                                \
            const int gpos = pos ^ (m & 7);                                   \
            glds16(Ag + (size_t)(m0 + m) * CCH + k0 + gpos * 8,               \
                   &a_tile[sbase * 8]);                                       \
            glds16(Bg + (size_t)(n0 + m) * CCH + k0 + gpos * 8,               \
                   &b_tile[sbase * 8]);                                       \
        }                                                                     \
        __syncthreads();                                                      \
        bf16x8 af[2][4], bfr[2][4];                                           \
        _Pragma("unroll") for (int s = 0; s < 2; ++s)                         \
            _Pragma("unroll") for (int i = 0; i < 4; ++i) {                   \
                const int am = wm + i * 16 + l16;                             \
                const int bn = wn + i * 16 + l16;                             \
                const int c = s * 4 + quad;                                   \
                af[s][i]  = *reinterpret_cast<const bf16x8*>(                 \
                    &a_tile[(am * 8 + (c ^ (am & 7))) * 8]);                  \
                bfr[s][i] = *reinterpret_cast<const bf16x8*>(                 \
                    &b_tile[(bn * 8 + (c ^ (bn & 7))) * 8]);                  \
            }                                                                 \
        _Pragma("unroll") for (int s = 0; s < 2; ++s)                         \
            _Pragma("unroll") for (int mi = 0; mi < 4; ++mi)                  \
                _Pragma("unroll") for (int ni = 0; ni < 4; ++ni)              \
                    acc[mi][ni] = __builtin_amdgcn_mfma_f32_16x16x32_bf16(    \
                        af[s][mi], bfr[s][ni], acc[mi][ni], 0, 0, 0);         \
    }

// proj_qk: A = xT[b] (rows l), B = w_p (rows o) -> Y[l][o] bf16 [b][l][c]
__global__ __launch_bounds__(256) void proj_qk_kernel(
    const u16* __restrict__ xT, const u16* __restrict__ wb,
    const float* __restrict__ bq, const float* __restrict__ bk,
    u16* __restrict__ Qlc, u16* __restrict__ Klc)
{
    const int z = blockIdx.z, b = z >> 1, p = z & 1;
    const int n0 = blockIdx.x * 128, m0 = blockIdx.y * 128;   // n0: o, m0: l
    const u16* Ag = xT + (size_t)b * LQ * CCH;
    const u16* Bg = wb + (size_t)p * WELE;
    const float* bias = (p == 0) ? bq : bk;
    u16* Y = ((p == 0) ? Qlc : Klc) + (size_t)b * LQ * CCH;

    GEMM_CORE(Ag, Bg)

#pragma unroll
    for (int ni = 0; ni < 4; ++ni) {
        const int o = n0 + wn + ni * 16 + l16;
        const float bb = bias[o];
#pragma unroll
        for (int mi = 0; mi < 4; ++mi)
#pragma unroll
            for (int r = 0; r < 4; ++r) {
                const int l = m0 + wm + mi * 16 + quad * 4 + r;
                Y[(size_t)l * CCH + o] = f2bf_u(acc[mi][ni][r] + bb);
            }
    }
}

// proj_v: A = wv (rows o), B = xT[b] (rows l) -> V bf16 [b][c][l]
__global__ __launch_bounds__(256) void proj_v_kernel(
    const u16* __restrict__ xT, const u16* __restrict__ wb,
    const float* __restrict__ bv, u16* __restrict__ Vw)
{
    const int b = blockIdx.z;
    const int n0 = blockIdx.x * 128, m0 = blockIdx.y * 128;   // n0: l, m0: o
    const u16* Ag = wb + (size_t)2 * WELE;
    const u16* Bg = xT + (size_t)b * LQ * CCH;
    u16* Y = Vw + (size_t)b * CCH * LQ;

    GEMM_CORE(Ag, Bg)

#pragma unroll
    for (int mi = 0; mi < 4; ++mi) {
#pragma unroll
        for (int r = 0; r < 4; ++r) {
            const int o = m0 + wm + mi * 16 + quad * 4 + r;
            const float bb = bv[o];
#pragma unroll
            for (int ni = 0; ni < 4; ++ni) {
                const int l = n0 + wn + ni * 16 + l16;
                Y[(size_t)o * LQ + l] = f2bf_u(acc[mi][ni][r] + bb);
            }
        }
    }
}

// proj_out: A = wo, B = resb[b] ([l][c] bf16) -> out fp32 [b][c][l]
__global__ __launch_bounds__(256) void proj_out_kernel(
    const u16* __restrict__ resb, const u16* __restrict__ wb,
    const float* __restrict__ bo, float* __restrict__ out)
{
    const int b = blockIdx.z;
    const int n0 = blockIdx.x * 128, m0 = blockIdx.y * 128;
    const u16* Ag = wb + (size_t)3 * WELE;
    const u16* Bg = resb + (size_t)b * LQ * CCH;
    float* Y = out + (size_t)b * CCH * LQ;

    GEMM_CORE(Ag, Bg)

#pragma unroll
    for (int mi = 0; mi < 4; ++mi) {
#pragma unroll
        for (int r = 0; r < 4; ++r) {
            const int o = m0 + wm + mi * 16 + quad * 4 + r;
            const float bb = bo[o];
#pragma unroll
            for (int ni = 0; ni < 4; ++ni) {
                const int l = n0 + wn + ni * 16 + l16;
                Y[(size_t)o * LQ + l] = acc[mi][ni][r] + bb;
            }
        }
    }
}

// ---------------------------------------------------------------------------
// MFMA flash attention, 32x32x16, key-split waves, constant-STAB softmax.
// CTA = one (b,h) x 64 q-rows; wave w = (qh=w&1, kh=w>>1): 32 q x 32 keys/iter.
// S^T = K.Q^T -> C col = q = lane&31 (in-lane softmax), row = key.
// Partial O/l per (qh,kh) merged through LDS at the end (exp(-STAB) cancels).
// Layouts: Q/K [b][l][c] (contiguous d), V [b][c][l] ([d][key]-major).
// C/D 32x32: col=lane&31, row=(reg&3)+8*(reg>>2)+4*(lane>>5)  [m74/m101]
// ---------------------------------------------------------------------------
#define KSTRIDE 72
#define PSTR 40

__global__ __launch_bounds__(256, 4) void attn_kernel(
    const u16* __restrict__ Qlc, const u16* __restrict__ Klc,
    const u16* __restrict__ Vw,
    const float* __restrict__ erk, const float* __restrict__ erv,
    u16* __restrict__ resb)
{
    __shared__ __align__(16) u16 kv_lds[2 * 64 * KSTRIDE];  // K | V; later ored/kdiag
    __shared__ __align__(16) u16 p_lds[4 * 32 * PSTR];
    __shared__ float bias_lds[64 * 9];
    __shared__ float bandw_lds[64 * 9];
    __shared__ float erk_lds[9 * 64];
    __shared__ float erv_lds[9 * 64];
    __shared__ float l_red[64];

    u16* k16 = kv_lds;
    u16* v16 = kv_lds + 64 * KSTRIDE;
    float* ored = (float*)kv_lds;   // 64x64 fp32 = 16 KB (aliases k16/v16)
    u16* kdiag = kv_lds;            // 72 x KSTRIDE     (after ored merge)

    const int t = threadIdx.x;
    const int wave = t >> 6, lane = t & 63;
    const int hw = lane >> 5, l32 = lane & 31;
    const int qh = wave & 1, kh = wave >> 1;
    const int l0 = blockIdx.x * 64, h = blockIdx.y, b = blockIdx.z;

    const u16* Qb = Qlc + (size_t)b * LQ * CCH + h * HD;
    const u16* Kb = Klc + (size_t)b * LQ * CCH + h * HD;
    const u16* Vb = Vw + ((size_t)b * CCH + h * HD) * LQ;

    for (int i = t; i < 9 * 64; i += 256) {
        erk_lds[i] = erk[(size_t)h * 9 * 64 + i];
        erv_lds[i] = erv[(size_t)h * 9 * 64 + i];
    }

    const int qrow = qh * 32 + l32;     // CTA-local q row owned by this lane
    const int lgq = l0 + qrow;

    // Q B-frags: qa[c] = Q[q=l32][d = c*16 + hw*8 + j]
    bf16x8 qa[4];
#pragma unroll
    for (int c = 0; c < 4; ++c)
        qa[c] = *reinterpret_cast<const bf16x8*>(&Qb[(size_t)lgq * CCH + c * 16 + hw * 8]);

    __syncthreads();   // erk_lds ready

    // bias_lds[qrow][dl] = q . erk[dl]   (kh=0 waves produce)
    if (kh == 0) {
        float qf[32];
#pragma unroll
        for (int c = 0; c < 4; ++c) {
            union { bf16x8 v; u16x8 u; } a; a.v = qa[c];
#pragma unroll
            for (int j = 0; j < 8; ++j) qf[c * 8 + j] = bf2f(a.u[j]);
        }
        for (int dl = 0; dl < 9; ++dl) {
            float s = 0.f;
#pragma unroll
            for (int c = 0; c < 4; ++c)
#pragma unroll
                for (int j = 0; j < 8; ++j)
                    s += qf[c * 8 + j] * erk_lds[dl * 64 + c * 16 + hw * 8 + j];
            s += __shfl_xor(s, 32, 64);
            if (hw == 0) bias_lds[qrow * 9 + dl] = s;
        }
    }
    // (bias visible to all waves after iter-0 staging barriers)

    floatx16 O[2];
#pragma unroll
    for (int dt = 0; dt < 2; ++dt)
#pragma unroll
        for (int r = 0; r < 16; ++r) O[dt][r] = 0.f;
    float l_acc = 0.f;

    u16* pw = p_lds + wave * 32 * PSTR;

    for (int kb = 0; kb < 16; ++kb) {
        const int j0 = kb * 64;
        __syncthreads();
        // stage K[j][d] and V[d][j] (both contiguous 32B copies)
        {
            const int j = t >> 2, seg = t & 3;
            const u16x8* ks = reinterpret_cast<const u16x8*>(&Kb[(size_t)(j0 + j) * CCH + seg * 16]);
            *reinterpret_cast<u16x8*>(&k16[j * KSTRIDE + seg * 16])     = ks[0];
            *reinterpret_cast<u16x8*>(&k16[j * KSTRIDE + seg * 16 + 8]) = ks[1];
            const u16x8* vs = reinterpret_cast<const u16x8*>(&Vb[(size_t)j * LQ + j0 + seg * 16]);
            *reinterpret_cast<u16x8*>(&v16[j * KSTRIDE + seg * 16])     = vs[0];
            *reinterpret_cast<u16x8*>(&v16[j * KSTRIDE + seg * 16 + 8]) = vs[1];
        }
        __syncthreads();

        // S^T: 32 keys (kh half) x 32 q: 4 mfma over d=64
        floatx16 sc;
#pragma unroll
        for (int r = 0; r < 16; ++r) sc[r] = 0.f;
#pragma unroll
        for (int c = 0; c < 4; ++c) {
            const bf16x8 ka = *reinterpret_cast<const bf16x8*>(
                &k16[(kh * 32 + l32) * KSTRIDE + c * 16 + hw * 8]);
            sc = __builtin_amdgcn_mfma_f32_32x32x16_bf16(ka, qa[c], sc, 0, 0, 0);
        }

        // banded bias (wave-uniform skip far from diagonal)
        const int kbase = j0 + kh * 32;
        if (kbase + 31 >= l0 + qh * 32 - 4 && kbase <= l0 + qh * 32 + 35) {
#pragma unroll
            for (int r = 0; r < 16; ++r) {
                const int key = kbase + (r & 3) + 8 * (r >> 2) + 4 * hw;
                const int delta = key - lgq + 4;
                if (delta >= 0 && delta <= 8) sc[r] += bias_lds[qrow * 9 + delta];
            }
        }

        // p = exp(s*SCALE - STAB); in-lane l accumulate; P -> 4 x b64
        u16 pk[16];
#pragma unroll
        for (int r = 0; r < 16; ++r) {
            const float p = __expf(fmaf(sc[r], SCALE, -STAB));
            l_acc += p;
            pk[r] = f2bf_u(p);
        }
#pragma unroll
        for (int g = 0; g < 4; ++g)
            *reinterpret_cast<u16x4*>(&pw[l32 * PSTR + 8 * g + 4 * hw]) =
                *reinterpret_cast<const u16x4*>(&pk[4 * g]);
        // intra-wave P write->read: DS in-order

        // PV: A = P[q][key], B = V (B[k=key][n=d]); partial over kh's 32 keys
#pragma unroll
        for (int c2 = 0; c2 < 2; ++c2) {
            const bf16x8 pa = *reinterpret_cast<const bf16x8*>(
                &pw[l32 * PSTR + c2 * 16 + hw * 8]);
#pragma unroll
            for (int dt = 0; dt < 2; ++dt) {
                const bf16x8 vb = *reinterpret_cast<const bf16x8*>(
                    &v16[(dt * 32 + l32) * KSTRIDE + kh * 32 + c2 * 16 + hw * 8]);
                O[dt] = __builtin_amdgcn_mfma_f32_32x32x16_bf16(pa, vb, O[dt], 0, 0, 0);
            }
        }
    }

    // l: combine hw halves -> full kh-half sum for q = l32
    l_acc += __shfl_xor(l_acc, 32, 64);

    __syncthreads();   // loop reads of k16/v16 done -> alias as ored
    if (kh == 1) {
        if (hw == 0) l_red[qrow] = l_acc;
#pragma unroll
        for (int dt = 0; dt < 2; ++dt)
#pragma unroll
            for (int r = 0; r < 16; ++r) {
                const int row = (r & 3) + 8 * (r >> 2) + 4 * hw;
                ored[(qh * 32 + row) * 64 + dt * 32 + l32] = O[dt][r];
            }
    }
    __syncthreads();
    if (kh == 0) {
        const float linv = 1.0f / (l_acc + l_red[qrow]);
#pragma unroll
        for (int dt = 0; dt < 2; ++dt)
#pragma unroll
            for (int r = 0; r < 16; ++r) {
                const int row = (r & 3) + 8 * (r >> 2) + 4 * hw;
                O[dt][r] += ored[(qh * 32 + row) * 64 + dt * 32 + l32];
            }
        if (hw == 0) l_red[qrow] = linv;   // publish 1/l (same-wave consumers)
    }
    __syncthreads();   // ored reads done -> alias as kdiag

    // stage kdiag rows i=0..71 <-> K row l0-4+i (clamped; OOB masked later)
    {
        const int i0 = t >> 2, seg = t & 3;
        const int jc = min(max(l0 - 4 + i0, 0), LQ - 1);
        const u16x8* s0 = reinterpret_cast<const u16x8*>(&Kb[(size_t)jc * CCH + seg * 16]);
        *reinterpret_cast<u16x8*>(&kdiag[i0 * KSTRIDE + seg * 16])     = s0[0];
        *reinterpret_cast<u16x8*>(&kdiag[i0 * KSTRIDE + seg * 16 + 8]) = s0[1];
        if (t < 32) {
            const int i1 = 64 + (t >> 2);
            const int j2 = min(l0 - 4 + i1, LQ - 1);
            const u16x8* s1 = reinterpret_cast<const u16x8*>(&Kb[(size_t)j2 * CCH + seg * 16]);
            *reinterpret_cast<u16x8*>(&kdiag[i1 * KSTRIDE + seg * 16])     = s1[0];
            *reinterpret_cast<u16x8*>(&kdiag[i1 * KSTRIDE + seg * 16 + 8]) = s1[1];
        }
    }
    __syncthreads();

    if (kh == 0) {
        // band weights: p = exp((q.k + bias)*scale - STAB), OOB masked
        float qf[32];
#pragma unroll
        for (int c = 0; c < 4; ++c) {
            union { bf16x8 v; u16x8 u; } a; a.v = qa[c];
#pragma unroll
            for (int j = 0; j < 8; ++j) qf[c * 8 + j] = bf2f(a.u[j]);
        }
        for (int dl = 0; dl < 9; ++dl) {
            const int i = qrow + dl;
            float s = 0.f;
#pragma unroll
            for (int c = 0; c < 4; ++c) {
                union { bf16x8 v; u16x8 u; } kd;
                kd.v = *reinterpret_cast<const bf16x8*>(&kdiag[i * KSTRIDE + c * 16 + hw * 8]);
#pragma unroll
                for (int j = 0; j < 8; ++j) s += qf[c * 8 + j] * bf2f(kd.u[j]);
            }
            s += __shfl_xor(s, 32, 64);
            const int jgl = lgq + dl - 4;
            float pband = 0.f;
            if (jgl >= 0 && jgl < LQ)
                pband = __expf(fmaf(s + bias_lds[qrow * 9 + dl], SCALE, -STAB));
            if (hw == 0) bandw_lds[qrow * 9 + dl] = pband;
        }
        // same-wave bandw/l_red consumers below: DS in-order

        // epilogue: (O + band.erv) / l -> resb bf16 [b][l][c]
#pragma unroll
        for (int dt = 0; dt < 2; ++dt) {
#pragma unroll
            for (int r = 0; r < 16; ++r) {
                const int row = (r & 3) + 8 * (r >> 2) + 4 * hw;
                const int d = dt * 32 + l32;
                float val = O[dt][r];
#pragma unroll
                for (int dl = 0; dl < 9; ++dl)
                    val += bandw_lds[(qh * 32 + row) * 9 + dl] * erv_lds[dl * 64 + d];
                val *= l_red[qh * 32 + row];
                resb[((size_t)b * LQ + l0 + qh * 32 + row) * CCH + h * HD + d] = f2bf_u(val);
            }
        }
    }
}

// ---------------------------------------------------------------------------
extern "C" void kernel_launch(void* const* d_in, const int* in_sizes, int n_in,
                              void* d_out, int out_size, void* d_ws, size_t ws_size,
                              hipStream_t stream) {
    const float* x   = (const float*)d_in[0];
    const float* wq  = (const float*)d_in[1];
    const float* bq  = (const float*)d_in[2];
    const float* wk  = (const float*)d_in[3];
    const float* bk  = (const float*)d_in[4];
    const float* wv  = (const float*)d_in[5];
    const float* bv  = (const float*)d_in[6];
    const float* wo  = (const float*)d_in[7];
    const float* bo  = (const float*)d_in[8];
    const float* erk = (const float*)d_in[9];
    const float* erv = (const float*)d_in[10];
    float* out = (float*)d_out;

    // ws (u16): xT | wb(4) | Qlc | Klc | Vw | resb  (~36 MB)
    const size_t NEL = (size_t)NB * CCH * LQ;   // 3,145,728
    u16* xT   = (u16*)d_ws;
    u16* wb   = xT + NEL;
    u16* Qlc  = wb + (size_t)4 * WELE;
    u16* Klc  = Qlc + NEL;
    u16* Vw   = Klc + NEL;
    u16* resb = Vw + NEL;

    convert_w_kernel<<<dim3(WELE / 1024, 4), 256, 0, stream>>>(wq, wk, wv, wo, wb);
    transpose_x_kernel<<<dim3(16, 12, 4), 256, 0, stream>>>(x, xT);
    proj_qk_kernel<<<dim3(6, 8, 8), 256, 0, stream>>>(xT, wb, bq, bk, Qlc, Klc);
    proj_v_kernel<<<dim3(8, 6, 4), 256, 0, stream>>>(xT, wb, bv, Vw);
    attn_kernel<<<dim3(LQ / 64, NH, NB), 256, 0, stream>>>(
        Qlc, Klc, Vw, erk, erv, resb);
    proj_out_kernel<<<dim3(8, 6, 4), 256, 0, stream>>>(resb, wb, bo, out);
}

// Round 8
// 202.117 us; speedup vs baseline: 1.0616x; 1.0616x over previous
//
#include <hip/hip_runtime.h>

// Problem constants
#define NB   4
#define NH   12
#define HD   64
#define CCH  768        // NH*HD
#define LQ   1024
#define SCALE 0.125f    // 1/sqrt(64)
#define STAB  4.0f      // constant softmax stabilizer (scores ~N(0,1), max~4)
#define WELE (CCH*CCH)  // 589824 elements per weight matrix

typedef unsigned short u16;
typedef __bf16 bf16x8 __attribute__((ext_vector_type(8)));
typedef unsigned short u16x8 __attribute__((ext_vector_type(8)));
typedef unsigned short u16x4 __attribute__((ext_vector_type(4)));
typedef float floatx4 __attribute__((ext_vector_type(4)));
typedef float floatx16 __attribute__((ext_vector_type(16)));

__device__ __forceinline__ float bf2f(u16 u) {
    union { unsigned int i; float f; } x; x.i = ((unsigned int)u) << 16; return x.f;
}
__device__ __forceinline__ u16 f2bf_u(float f) {
    union { float f; unsigned int i; } x; x.f = f;
    unsigned int i = x.i;
    return (u16)((i + 0x7FFFu + ((i >> 16) & 1u)) >> 16);   // RNE
}
// async global -> LDS, 16 B per lane; lds dst must be wave-uniform base
__device__ __forceinline__ void glds16(const u16* g, u16* l) {
    __builtin_amdgcn_global_load_lds(
        (const __attribute__((address_space(1))) unsigned int*)g,
        (__attribute__((address_space(3))) unsigned int*)l, 16, 0, 0);
}

// ---------------------------------------------------------------------------
// one-time weight conversion fp32 -> bf16 ([4][768*768]: wq,wk,wv,wo)
// ---------------------------------------------------------------------------
__global__ __launch_bounds__(256) void convert_w_kernel(
    const float* __restrict__ wq, const float* __restrict__ wk,
    const float* __restrict__ wv, const float* __restrict__ wo,
    u16* __restrict__ wb)
{
    const int p = blockIdx.y;
    const float* src = (p == 0) ? wq : (p == 1) ? wk : (p == 2) ? wv : wo;
    u16* dst = wb + (size_t)p * WELE;
    const int idx = (blockIdx.x * 256 + threadIdx.x) * 4;
    const float4 v = *reinterpret_cast<const float4*>(src + idx);
    u16x4 o;
    o[0] = f2bf_u(v.x); o[1] = f2bf_u(v.y); o[2] = f2bf_u(v.z); o[3] = f2bf_u(v.w);
    *reinterpret_cast<u16x4*>(dst + idx) = o;
}

// ---------------------------------------------------------------------------
// x [b][c][l] fp32  ->  xT [b][l][c] bf16   (64x64 LDS tile transpose)
// ---------------------------------------------------------------------------
__global__ __launch_bounds__(256) void transpose_x_kernel(
    const float* __restrict__ x, u16* __restrict__ xT)
{
    __shared__ u16 tile[64 * 68];
    const int l0 = blockIdx.x * 64, c0 = blockIdx.y * 64, b = blockIdx.z;
    const int t = threadIdx.x;
    const float* xb = x + (size_t)b * CCH * LQ;
    {
        const int l = t & 63, cg = t >> 6;
        for (int i = 0; i < 16; ++i) {
            const int c = cg * 16 + i;
            tile[c * 68 + l] = f2bf_u(xb[(size_t)(c0 + c) * LQ + l0 + l]);
        }
    }
    __syncthreads();
    {
        const int c = t & 63, lg = t >> 6;
        for (int i = 0; i < 16; ++i) {
            const int l = lg * 16 + i;
            xT[((size_t)b * LQ + l0 + l) * CCH + c0 + c] = tile[c * 68 + l];
        }
    }
}

// ---------------------------------------------------------------------------
// Tiled MFMA GEMM core: C = A (M x K) . B^T (N x K), both bf16 row-major-in-K.
// CTA 128x128, BK=64, global_load_lds staging with XOR-8 chunk swizzle.
// 4 waves (2x2), each 64x64 = 4x4 MFMA 16x16x32. 2-barrier K-loop (m97).
// ---------------------------------------------------------------------------
#define GEMM_CORE(Ag, Bg)                                                     \
    __shared__ __align__(16) u16 a_tile[128 * 64];                            \
    __shared__ __align__(16) u16 b_tile[128 * 64];                            \
    const int t = threadIdx.x;                                                \
    const int wave = t >> 6, lane = t & 63;                                   \
    const int quad = lane >> 4, l16 = lane & 15;                              \
    const int wm = (wave >> 1) * 64, wn = (wave & 1) * 64;                    \
    floatx4 acc[4][4];                                                        \
    _Pragma("unroll") for (int mi = 0; mi < 4; ++mi)                          \
        _Pragma("unroll") for (int ni = 0; ni < 4; ++ni)                      \
            _Pragma("unroll") for (int r = 0; r < 4; ++r) acc[mi][ni][r] = 0.f;\
    for (int k0 = 0; k0 < CCH; k0 += 64) {                                    \
        __syncthreads();                                                      \
        _Pragma("unroll") for (int i = 0; i < 4; ++i) {                       \
            const int sbase = wave * 256 + i * 64;                            \
            const int s = sbase + lane;                                       \
            const int m = s >> 3, pos = s & 7;                                \
            const int gpos = pos ^ (m & 7);                                   \
            glds16(Ag + (size_t)(m0 + m) * CCH + k0 + gpos * 8,               \
                   &a_tile[sbase * 8]);                                       \
            glds16(Bg + (size_t)(n0 + m) * CCH + k0 + gpos * 8,               \
                   &b_tile[sbase * 8]);                                       \
        }                                                                     \
        __syncthreads();                                                      \
        bf16x8 af[2][4], bfr[2][4];                                           \
        _Pragma("unroll") for (int s = 0; s < 2; ++s)                         \
            _Pragma("unroll") for (int i = 0; i < 4; ++i) {                   \
                const int am = wm + i * 16 + l16;                             \
                const int bn = wn + i * 16 + l16;                             \
                const int c = s * 4 + quad;                                   \
                af[s][i]  = *reinterpret_cast<const bf16x8*>(                 \
                    &a_tile[(am * 8 + (c ^ (am & 7))) * 8]);                  \
                bfr[s][i] = *reinterpret_cast<const bf16x8*>(                 \
                    &b_tile[(bn * 8 + (c ^ (bn & 7))) * 8]);                  \
            }                                                                 \
        _Pragma("unroll") for (int s = 0; s < 2; ++s)                         \
            _Pragma("unroll") for (int mi = 0; mi < 4; ++mi)                  \
                _Pragma("unroll") for (int ni = 0; ni < 4; ++ni)              \
                    acc[mi][ni] = __builtin_amdgcn_mfma_f32_16x16x32_bf16(    \
                        af[s][mi], bfr[s][ni], acc[mi][ni], 0, 0, 0);         \
    }

// proj_qk: A = xT[b] (rows l), B = w_p (rows o) -> Y[l][o] bf16 [b][l][c]
__global__ __launch_bounds__(256) void proj_qk_kernel(
    const u16* __restrict__ xT, const u16* __restrict__ wb,
    const float* __restrict__ bq, const float* __restrict__ bk,
    u16* __restrict__ Qlc, u16* __restrict__ Klc)
{
    const int z = blockIdx.z, b = z >> 1, p = z & 1;
    const int n0 = blockIdx.x * 128, m0 = blockIdx.y * 128;   // n0: o, m0: l
    const u16* Ag = xT + (size_t)b * LQ * CCH;
    const u16* Bg = wb + (size_t)p * WELE;
    const float* bias = (p == 0) ? bq : bk;
    u16* Y = ((p == 0) ? Qlc : Klc) + (size_t)b * LQ * CCH;

    GEMM_CORE(Ag, Bg)

#pragma unroll
    for (int ni = 0; ni < 4; ++ni) {
        const int o = n0 + wn + ni * 16 + l16;
        const float bb = bias[o];
#pragma unroll
        for (int mi = 0; mi < 4; ++mi)
#pragma unroll
            for (int r = 0; r < 4; ++r) {
                const int l = m0 + wm + mi * 16 + quad * 4 + r;
                Y[(size_t)l * CCH + o] = f2bf_u(acc[mi][ni][r] + bb);
            }
    }
}

// proj_v: A = wv (rows o), B = xT[b] (rows l) -> V bf16 [b][c][l]
__global__ __launch_bounds__(256) void proj_v_kernel(
    const u16* __restrict__ xT, const u16* __restrict__ wb,
    const float* __restrict__ bv, u16* __restrict__ Vw)
{
    const int b = blockIdx.z;
    const int n0 = blockIdx.x * 128, m0 = blockIdx.y * 128;   // n0: l, m0: o
    const u16* Ag = wb + (size_t)2 * WELE;
    const u16* Bg = xT + (size_t)b * LQ * CCH;
    u16* Y = Vw + (size_t)b * CCH * LQ;

    GEMM_CORE(Ag, Bg)

#pragma unroll
    for (int mi = 0; mi < 4; ++mi) {
#pragma unroll
        for (int r = 0; r < 4; ++r) {
            const int o = m0 + wm + mi * 16 + quad * 4 + r;
            const float bb = bv[o];
#pragma unroll
            for (int ni = 0; ni < 4; ++ni) {
                const int l = n0 + wn + ni * 16 + l16;
                Y[(size_t)o * LQ + l] = f2bf_u(acc[mi][ni][r] + bb);
            }
        }
    }
}

// proj_out: A = wo, B = resb[b] ([l][c] bf16) -> out fp32 [b][c][l]
__global__ __launch_bounds__(256) void proj_out_kernel(
    const u16* __restrict__ resb, const u16* __restrict__ wb,
    const float* __restrict__ bo, float* __restrict__ out)
{
    const int b = blockIdx.z;
    const int n0 = blockIdx.x * 128, m0 = blockIdx.y * 128;
    const u16* Ag = wb + (size_t)3 * WELE;
    const u16* Bg = resb + (size_t)b * LQ * CCH;
    float* Y = out + (size_t)b * CCH * LQ;

    GEMM_CORE(Ag, Bg)

#pragma unroll
    for (int mi = 0; mi < 4; ++mi) {
#pragma unroll
        for (int r = 0; r < 4; ++r) {
            const int o = m0 + wm + mi * 16 + quad * 4 + r;
            const float bb = bo[o];
#pragma unroll
            for (int ni = 0; ni < 4; ++ni) {
                const int l = n0 + wn + ni * 16 + l16;
                Y[(size_t)o * LQ + l] = acc[mi][ni][r] + bb;
            }
        }
    }
}

// ---------------------------------------------------------------------------
// MFMA flash attention, 32x32x16, key-split waves, constant-STAB softmax.
// CTA = one (b,h) x 64 q-rows; wave w = (qh=w&1, kh=w>>1): 32 q x 32 keys/iter.
// S^T = K.Q^T -> C col = q = lane&31 (in-lane softmax), row = key.
// Partial O/l per (qh,kh) merged through LDS at the end (exp(-STAB) cancels).
// Layouts: Q/K [b][l][c] (contiguous d), V [b][c][l] ([d][key]-major).
// C/D 32x32: col=lane&31, row=(reg&3)+8*(reg>>2)+4*(lane>>5)  [m74/m101]
// NOTE: no min-waves clamp in launch_bounds — (256,4) forced 64 VGPRs and
// spilled the O accumulators to scratch (94 MB WRITE_SIZE, round 7).
// ---------------------------------------------------------------------------
#define KSTRIDE 72
#define PSTR 40

__global__ __launch_bounds__(256) void attn_kernel(
    const u16* __restrict__ Qlc, const u16* __restrict__ Klc,
    const u16* __restrict__ Vw,
    const float* __restrict__ erk, const float* __restrict__ erv,
    u16* __restrict__ resb)
{
    __shared__ __align__(16) u16 kv_lds[2 * 64 * KSTRIDE];  // K | V; later ored/kdiag
    __shared__ __align__(16) u16 p_lds[4 * 32 * PSTR];
    __shared__ float bias_lds[64 * 9];
    __shared__ float bandw_lds[64 * 9];
    __shared__ float erk_lds[9 * 64];
    __shared__ float erv_lds[9 * 64];
    __shared__ float l_red[64];

    u16* k16 = kv_lds;
    u16* v16 = kv_lds + 64 * KSTRIDE;
    float* ored = (float*)kv_lds;   // 64x64 fp32 = 16 KB (aliases k16/v16)
    u16* kdiag = kv_lds;            // 72 x KSTRIDE     (after ored merge)

    const int t = threadIdx.x;
    const int wave = t >> 6, lane = t & 63;
    const int hw = lane >> 5, l32 = lane & 31;
    const int qh = wave & 1, kh = wave >> 1;
    const int l0 = blockIdx.x * 64, h = blockIdx.y, b = blockIdx.z;

    const u16* Qb = Qlc + (size_t)b * LQ * CCH + h * HD;
    const u16* Kb = Klc + (size_t)b * LQ * CCH + h * HD;
    const u16* Vb = Vw + ((size_t)b * CCH + h * HD) * LQ;

    for (int i = t; i < 9 * 64; i += 256) {
        erk_lds[i] = erk[(size_t)h * 9 * 64 + i];
        erv_lds[i] = erv[(size_t)h * 9 * 64 + i];
    }

    const int qrow = qh * 32 + l32;     // CTA-local q row owned by this lane
    const int lgq = l0 + qrow;

    // Q B-frags: qa[c] = Q[q=l32][d = c*16 + hw*8 + j]
    bf16x8 qa[4];
#pragma unroll
    for (int c = 0; c < 4; ++c)
        qa[c] = *reinterpret_cast<const bf16x8*>(&Qb[(size_t)lgq * CCH + c * 16 + hw * 8]);

    __syncthreads();   // erk_lds ready

    // bias_lds[qrow][dl] = q . erk[dl]   (kh=0 waves produce)
    if (kh == 0) {
        float qf[32];
#pragma unroll
        for (int c = 0; c < 4; ++c) {
            union { bf16x8 v; u16x8 u; } a; a.v = qa[c];
#pragma unroll
            for (int j = 0; j < 8; ++j) qf[c * 8 + j] = bf2f(a.u[j]);
        }
        for (int dl = 0; dl < 9; ++dl) {
            float s = 0.f;
#pragma unroll
            for (int c = 0; c < 4; ++c)
#pragma unroll
                for (int j = 0; j < 8; ++j)
                    s += qf[c * 8 + j] * erk_lds[dl * 64 + c * 16 + hw * 8 + j];
            s += __shfl_xor(s, 32, 64);
            if (hw == 0) bias_lds[qrow * 9 + dl] = s;
        }
    }
    // (bias visible to all waves after iter-0 staging barriers)

    floatx16 O[2];
#pragma unroll
    for (int dt = 0; dt < 2; ++dt)
#pragma unroll
        for (int r = 0; r < 16; ++r) O[dt][r] = 0.f;
    float l_acc = 0.f;

    u16* pw = p_lds + wave * 32 * PSTR;

    for (int kb = 0; kb < 16; ++kb) {
        const int j0 = kb * 64;
        __syncthreads();
        // stage K[j][d] and V[d][j] (both contiguous 32B copies)
        {
            const int j = t >> 2, seg = t & 3;
            const u16x8* ks = reinterpret_cast<const u16x8*>(&Kb[(size_t)(j0 + j) * CCH + seg * 16]);
            *reinterpret_cast<u16x8*>(&k16[j * KSTRIDE + seg * 16])     = ks[0];
            *reinterpret_cast<u16x8*>(&k16[j * KSTRIDE + seg * 16 + 8]) = ks[1];
            const u16x8* vs = reinterpret_cast<const u16x8*>(&Vb[(size_t)j * LQ + j0 + seg * 16]);
            *reinterpret_cast<u16x8*>(&v16[j * KSTRIDE + seg * 16])     = vs[0];
            *reinterpret_cast<u16x8*>(&v16[j * KSTRIDE + seg * 16 + 8]) = vs[1];
        }
        __syncthreads();

        // S^T: 32 keys (kh half) x 32 q: 4 mfma over d=64
        floatx16 sc;
#pragma unroll
        for (int r = 0; r < 16; ++r) sc[r] = 0.f;
#pragma unroll
        for (int c = 0; c < 4; ++c) {
            const bf16x8 ka = *reinterpret_cast<const bf16x8*>(
                &k16[(kh * 32 + l32) * KSTRIDE + c * 16 + hw * 8]);
            sc = __builtin_amdgcn_mfma_f32_32x32x16_bf16(ka, qa[c], sc, 0, 0, 0);
        }

        // banded bias (wave-uniform skip far from diagonal)
        const int kbase = j0 + kh * 32;
        if (kbase + 31 >= l0 + qh * 32 - 4 && kbase <= l0 + qh * 32 + 35) {
#pragma unroll
            for (int r = 0; r < 16; ++r) {
                const int key = kbase + (r & 3) + 8 * (r >> 2) + 4 * hw;
                const int delta = key - lgq + 4;
                if (delta >= 0 && delta <= 8) sc[r] += bias_lds[qrow * 9 + delta];
            }
        }

        // p = exp(s*SCALE - STAB); in-lane l accumulate; P -> 4 x b64
        u16 pk[16];
#pragma unroll
        for (int r = 0; r < 16; ++r) {
            const float p = __expf(fmaf(sc[r], SCALE, -STAB));
            l_acc += p;
            pk[r] = f2bf_u(p);
        }
#pragma unroll
        for (int g = 0; g < 4; ++g)
            *reinterpret_cast<u16x4*>(&pw[l32 * PSTR + 8 * g + 4 * hw]) =
                *reinterpret_cast<const u16x4*>(&pk[4 * g]);
        // intra-wave P write->read: DS in-order

        // PV: A = P[q][key], B = V (B[k=key][n=d]); partial over kh's 32 keys
#pragma unroll
        for (int c2 = 0; c2 < 2; ++c2) {
            const bf16x8 pa = *reinterpret_cast<const bf16x8*>(
                &pw[l32 * PSTR + c2 * 16 + hw * 8]);
#pragma unroll
            for (int dt = 0; dt < 2; ++dt) {
                const bf16x8 vb = *reinterpret_cast<const bf16x8*>(
                    &v16[(dt * 32 + l32) * KSTRIDE + kh * 32 + c2 * 16 + hw * 8]);
                O[dt] = __builtin_amdgcn_mfma_f32_32x32x16_bf16(pa, vb, O[dt], 0, 0, 0);
            }
        }
    }

    // l: combine hw halves -> full kh-half sum for q = l32
    l_acc += __shfl_xor(l_acc, 32, 64);

    __syncthreads();   // loop reads of k16/v16 done -> alias as ored
    if (kh == 1) {
        if (hw == 0) l_red[qrow] = l_acc;
#pragma unroll
        for (int dt = 0; dt < 2; ++dt)
#pragma unroll
            for (int r = 0; r < 16; ++r) {
                const int row = (r & 3) + 8 * (r >> 2) + 4 * hw;
                ored[(qh * 32 + row) * 64 + dt * 32 + l32] = O[dt][r];
            }
    }
    __syncthreads();
    if (kh == 0) {
        const float linv = 1.0f / (l_acc + l_red[qrow]);
#pragma unroll
        for (int dt = 0; dt < 2; ++dt)
#pragma unroll
            for (int r = 0; r < 16; ++r) {
                const int row = (r & 3) + 8 * (r >> 2) + 4 * hw;
                O[dt][r] += ored[(qh * 32 + row) * 64 + dt * 32 + l32];
            }
        if (hw == 0) l_red[qrow] = linv;   // publish 1/l (same-wave consumers)
    }
    __syncthreads();   // ored reads done -> alias as kdiag

    // stage kdiag rows i=0..71 <-> K row l0-4+i (clamped; OOB masked later)
    {
        const int i0 = t >> 2, seg = t & 3;
        const int jc = min(max(l0 - 4 + i0, 0), LQ - 1);
        const u16x8* s0 = reinterpret_cast<const u16x8*>(&Kb[(size_t)jc * CCH + seg * 16]);
        *reinterpret_cast<u16x8*>(&kdiag[i0 * KSTRIDE + seg * 16])     = s0[0];
        *reinterpret_cast<u16x8*>(&kdiag[i0 * KSTRIDE + seg * 16 + 8]) = s0[1];
        if (t < 32) {
            const int i1 = 64 + (t >> 2);
            const int j2 = min(l0 - 4 + i1, LQ - 1);
            const u16x8* s1 = reinterpret_cast<const u16x8*>(&Kb[(size_t)j2 * CCH + seg * 16]);
            *reinterpret_cast<u16x8*>(&kdiag[i1 * KSTRIDE + seg * 16])     = s1[0];
            *reinterpret_cast<u16x8*>(&kdiag[i1 * KSTRIDE + seg * 16 + 8]) = s1[1];
        }
    }
    __syncthreads();

    if (kh == 0) {
        // band weights: p = exp((q.k + bias)*scale - STAB), OOB masked
        float qf[32];
#pragma unroll
        for (int c = 0; c < 4; ++c) {
            union { bf16x8 v; u16x8 u; } a; a.v = qa[c];
#pragma unroll
            for (int j = 0; j < 8; ++j) qf[c * 8 + j] = bf2f(a.u[j]);
        }
        for (int dl = 0; dl < 9; ++dl) {
            const int i = qrow + dl;
            float s = 0.f;
#pragma unroll
            for (int c = 0; c < 4; ++c) {
                union { bf16x8 v; u16x8 u; } kd;
                kd.v = *reinterpret_cast<const bf16x8*>(&kdiag[i * KSTRIDE + c * 16 + hw * 8]);
#pragma unroll
                for (int j = 0; j < 8; ++j) s += qf[c * 8 + j] * bf2f(kd.u[j]);
            }
            s += __shfl_xor(s, 32, 64);
            const int jgl = lgq + dl - 4;
            float pband = 0.f;
            if (jgl >= 0 && jgl < LQ)
                pband = __expf(fmaf(s + bias_lds[qrow * 9 + dl], SCALE, -STAB));
            if (hw == 0) bandw_lds[qrow * 9 + dl] = pband;
        }
        // same-wave bandw/l_red consumers below: DS in-order

        // epilogue: (O + band.erv) / l -> resb bf16 [b][l][c]
#pragma unroll
        for (int dt = 0; dt < 2; ++dt) {
#pragma unroll
            for (int r = 0; r < 16; ++r) {
                const int row = (r & 3) + 8 * (r >> 2) + 4 * hw;
                const int d = dt * 32 + l32;
                float val = O[dt][r];
#pragma unroll
                for (int dl = 0; dl < 9; ++dl)
                    val += bandw_lds[(qh * 32 + row) * 9 + dl] * erv_lds[dl * 64 + d];
                val *= l_red[qh * 32 + row];
                resb[((size_t)b * LQ + l0 + qh * 32 + row) * CCH + h * HD + d] = f2bf_u(val);
            }
        }
    }
}

// ---------------------------------------------------------------------------
extern "C" void kernel_launch(void* const* d_in, const int* in_sizes, int n_in,
                              void* d_out, int out_size, void* d_ws, size_t ws_size,
                              hipStream_t stream) {
    const float* x   = (const float*)d_in[0];
    const float* wq  = (const float*)d_in[1];
    const float* bq  = (const float*)d_in[2];
    const float* wk  = (const float*)d_in[3];
    const float* bk  = (const float*)d_in[4];
    const float* wv  = (const float*)d_in[5];
    const float* bv  = (const float*)d_in[6];
    const float* wo  = (const float*)d_in[7];
    const float* bo  = (const float*)d_in[8];
    const float* erk = (const float*)d_in[9];
    const float* erv = (const float*)d_in[10];
    float* out = (float*)d_out;

    // ws (u16): xT | wb(4) | Qlc | Klc | Vw | resb  (~36 MB)
    const size_t NEL = (size_t)NB * CCH * LQ;   // 3,145,728
    u16* xT   = (u16*)d_ws;
    u16* wb   = xT + NEL;
    u16* Qlc  = wb + (size_t)4 * WELE;
    u16* Klc  = Qlc + NEL;
    u16* Vw   = Klc + NEL;
    u16* resb = Vw + NEL;

    convert_w_kernel<<<dim3(WELE / 1024, 4), 256, 0, stream>>>(wq, wk, wv, wo, wb);
    transpose_x_kernel<<<dim3(16, 12, 4), 256, 0, stream>>>(x, xT);
    proj_qk_kernel<<<dim3(6, 8, 8), 256, 0, stream>>>(xT, wb, bq, bk, Qlc, Klc);
    proj_v_kernel<<<dim3(8, 6, 4), 256, 0, stream>>>(xT, wb, bv, Vw);
    attn_kernel<<<dim3(LQ / 64, NH, NB), 256, 0, stream>>>(
        Qlc, Klc, Vw, erk, erv, resb);
    proj_out_kernel<<<dim3(8, 6, 4), 256, 0, stream>>>(resb, wb, bo, out);
}